// Round 3
// baseline (443.340 us; speedup 1.0000x reference)
//
#include <hip/hip_runtime.h>
#include <hip/hip_bf16.h>

// Problem: B=4, S=2048, D=1024, H=16, E=64
#define B_ 4
#define S_ 2048
#define D_ 1024
#define H_ 16
#define E_ 64
#define M_ (B_*S_)      // 8192 rows
#define NQKV_ 3072

typedef __attribute__((ext_vector_type(8))) short bf16x8;
typedef __attribute__((ext_vector_type(4))) float f32x4;
typedef __attribute__((ext_vector_type(4))) unsigned short u16x4;
typedef unsigned short u16;

static __device__ __forceinline__ u16 f2bf(float f) {
  unsigned u = __builtin_bit_cast(unsigned, f);
  unsigned r = (u + 0x7FFFu + ((u >> 16) & 1u)) >> 16;
  return (u16)r;
}

// ---------------- conversion kernels ----------------

__global__ __launch_bounds__(256) void cvt4(const float* __restrict__ in,
                                            u16* __restrict__ out, int n4) {
  int i = blockIdx.x * 256 + threadIdx.x;
  if (i >= n4) return;
  f32x4 v = ((const f32x4*)in)[i];
  u16x4 o;
  o.x = f2bf(v.x); o.y = f2bf(v.y); o.z = f2bf(v.z); o.w = f2bf(v.w);
  ((u16x4*)out)[i] = o;
}

// Wq/Wk/Wv [H,D,E] -> Wt [3072][1024] (B^T layout: Wt[n][k] = W[k][n]),
// n = h*64+e (+1024 for K, +2048 for V), k = d.
__global__ __launch_bounds__(256) void cvt_wqkv(const float* __restrict__ Wq,
                                                const float* __restrict__ Wk,
                                                const float* __restrict__ Wv,
                                                u16* __restrict__ Wt) {
  int idx = blockIdx.x * 256 + threadIdx.x;   // 0..1048575 over [H][D][E]
  int e = idx & 63, d = (idx >> 6) & 1023, h = idx >> 16;
  int n = h * 64 + e;
  Wt[(size_t)n * 1024 + d]          = f2bf(Wq[idx]);
  Wt[(size_t)(1024 + n) * 1024 + d] = f2bf(Wk[idx]);
  Wt[(size_t)(2048 + n) * 1024 + d] = f2bf(Wv[idx]);
}

// ---------------- GEMM: C[M,N] = A[M,K] * Bt[N,K]^T ----------------
// m97 structure: 128x128 tile, BK=32, 4 waves (2x2 of 64x64), global_load_lds w=16.

template<bool FP32OUT>
__global__ __launch_bounds__(256) void gemm_bt(const u16* __restrict__ A,
                                               const u16* __restrict__ Bt,
                                               void* __restrict__ Cv,
                                               const float* __restrict__ bias,
                                               int M, int N, int K) {
  __shared__ u16 As[128 * 32];
  __shared__ u16 Bs[128 * 32];
  const int tid = threadIdx.x;
  const int lane = tid & 63, wid = tid >> 6;
  const int bm = blockIdx.x, bn = blockIdx.y;
  const int wr = wid >> 1, wc = wid & 1;
  const int ll = lane & 15, lg = lane >> 4;

  f32x4 acc[4][4] = {};

  const int srow = lane >> 2;          // row within 16-row chunk
  const int scol = (lane & 3) * 8;     // element col within BK=32

  for (int k0 = 0; k0 < K; k0 += 32) {
#pragma unroll
    for (int p = 0; p < 2; ++p) {
      int row = p * 64 + wid * 16 + srow;
      const u16* ga = A + (size_t)(bm * 128 + row) * K + k0 + scol;
      __builtin_amdgcn_global_load_lds(
          (const __attribute__((address_space(1))) void*)ga,
          (__attribute__((address_space(3))) void*)(As + p * 2048 + wid * 512),
          16, 0, 0);
      const u16* gb = Bt + (size_t)(bn * 128 + row) * K + k0 + scol;
      __builtin_amdgcn_global_load_lds(
          (const __attribute__((address_space(1))) void*)gb,
          (__attribute__((address_space(3))) void*)(Bs + p * 2048 + wid * 512),
          16, 0, 0);
    }
    __syncthreads();
    bf16x8 af[4], bfr[4];
#pragma unroll
    for (int mi = 0; mi < 4; ++mi)
      af[mi] = *(const bf16x8*)&As[(wr * 64 + mi * 16 + ll) * 32 + lg * 8];
#pragma unroll
    for (int ni = 0; ni < 4; ++ni)
      bfr[ni] = *(const bf16x8*)&Bs[(wc * 64 + ni * 16 + ll) * 32 + lg * 8];
#pragma unroll
    for (int mi = 0; mi < 4; ++mi)
#pragma unroll
      for (int ni = 0; ni < 4; ++ni)
        acc[mi][ni] = __builtin_amdgcn_mfma_f32_16x16x32_bf16(af[mi], bfr[ni],
                                                              acc[mi][ni], 0, 0, 0);
    __syncthreads();
  }

  // epilogue: C/D layout col = lane&15, row = (lane>>4)*4 + reg
  const int crow0 = bm * 128 + wr * 64;
  const int ccol0 = bn * 128 + wc * 64 + ll;
#pragma unroll
  for (int mi = 0; mi < 4; ++mi) {
#pragma unroll
    for (int ni = 0; ni < 4; ++ni) {
      int c = ccol0 + ni * 16;
#pragma unroll
      for (int j = 0; j < 4; ++j) {
        int r = crow0 + mi * 16 + lg * 4 + j;
        if (FP32OUT) {
          ((float*)Cv)[(size_t)r * N + c] = acc[mi][ni][j] + bias[c];
        } else {
          ((u16*)Cv)[(size_t)r * N + c] = f2bf(acc[mi][ni][j]);
        }
      }
    }
  }
}

// ---------------- flash attention (causal) ----------------
// grid (32 q-tiles, 64 b*h), 256 threads = 4 waves x 16 q-rows.
// QKV: [8192][3072] bf16; Q cols h*64, K cols 1024+h*64, V cols 2048+h*64.
// AO:  [8192][1024] bf16 (b,s,h*64+e)

__global__ __launch_bounds__(256) void attn(const u16* __restrict__ QKV,
                                            u16* __restrict__ AO) {
  __shared__ u16 Klds[64 * 64];      // [key][e], XOR-swizzled rows (128B)
  __shared__ u16 Vlds[64 * 64];      // V^T: [e][key], XOR-swizzled
  __shared__ u16 Plds[4][16 * 64];   // per-wave P [qrow][key], swizzled

  const int qt = blockIdx.x, bh = blockIdx.y;
  const int b = bh >> 4, h = bh & 15;
  const int tid = threadIdx.x, lane = tid & 63, wid = tid >> 6;
  const int ll = lane & 15, lg = lane >> 4;
  const int qbase = qt * 64;

  // Q fragments (A-layout): row = lane&15, k-chunk = (lane>>4)*8
  const int qrow = qbase + wid * 16 + ll;
  const u16* qptr = QKV + (size_t)(b * S_ + qrow) * NQKV_ + h * E_;
  bf16x8 qf[2];
  qf[0] = *(const bf16x8*)(qptr + lg * 8);
  qf[1] = *(const bf16x8*)(qptr + 32 + lg * 8);

  float m_run[4], l_run[4];
  f32x4 o_acc[4] = {};
#pragma unroll
  for (int j = 0; j < 4; ++j) { m_run[j] = -INFINITY; l_run[j] = 0.f; }

  for (int kt = 0; kt <= qt; ++kt) {
    const int kb = kt * 64;
    // stage K tile (row-major swizzled) and V tile (transposed swizzled)
#pragma unroll
    for (int p = 0; p < 2; ++p) {
      int idx = p * 256 + tid;
      int row = idx >> 3;            // key-local 0..63
      int c = idx & 7;               // 16B chunk
      const u16* kp = QKV + (size_t)(b * S_ + kb + row) * NQKV_ + 1024 + h * E_ + c * 8;
      bf16x8 kv = *(const bf16x8*)kp;
      *(bf16x8*)((char*)Klds + row * 128 + ((c * 16) ^ ((row & 7) << 4))) = kv;
      const u16* vp = QKV + (size_t)(b * S_ + kb + row) * NQKV_ + 2048 + h * E_ + c * 8;
      bf16x8 vv = *(const bf16x8*)vp;
#pragma unroll
      for (int j = 0; j < 8; ++j) {
        int e = c * 8 + j;
        *((u16*)((char*)Vlds + e * 128 + ((row * 2) ^ ((e & 7) << 4)))) =
            ((u16*)&vv)[j];
      }
    }
    __syncthreads();

    // S = Q K^T  (rows = local q 0..15, cols = key)
    f32x4 s[4] = {};
#pragma unroll
    for (int ks = 0; ks < 2; ++ks) {
#pragma unroll
      for (int nt = 0; nt < 4; ++nt) {
        int krow = nt * 16 + ll;
        bf16x8 kf = *(const bf16x8*)((char*)Klds + krow * 128 +
                                     ((ks * 64 + lg * 16) ^ ((krow & 7) << 4)));
        s[nt] = __builtin_amdgcn_mfma_f32_16x16x32_bf16(qf[ks], kf, s[nt], 0, 0, 0);
      }
    }

    // scale + causal mask (only diagonal tile needs masking)
    const bool diag = (kt == qt);
#pragma unroll
    for (int nt = 0; nt < 4; ++nt) {
      int keyg = kb + nt * 16 + ll;
#pragma unroll
      for (int j = 0; j < 4; ++j) {
        float sv = s[nt][j] * 0.125f;   // 1/sqrt(64)
        if (diag && keyg > qbase + wid * 16 + lg * 4 + j) sv = -1e30f;
        s[nt][j] = sv;
      }
    }

    // online softmax: row r = lg*4+j lives in the 16 lanes sharing lg
    float corr[4];
#pragma unroll
    for (int j = 0; j < 4; ++j) {
      float tm = fmaxf(fmaxf(s[0][j], s[1][j]), fmaxf(s[2][j], s[3][j]));
#pragma unroll
      for (int msk = 1; msk < 16; msk <<= 1) tm = fmaxf(tm, __shfl_xor(tm, msk, 64));
      float mn = fmaxf(m_run[j], tm);
      corr[j] = __expf(m_run[j] - mn);
      m_run[j] = mn;
    }
    float tsum[4] = {0.f, 0.f, 0.f, 0.f};
#pragma unroll
    for (int nt = 0; nt < 4; ++nt) {
#pragma unroll
      for (int j = 0; j < 4; ++j) {
        float pv = __expf(s[nt][j] - m_run[j]);
        tsum[j] += pv;
        int prow = lg * 4 + j;
        int pcol = nt * 16 + ll;
        *((u16*)((char*)(&Plds[wid][0]) + prow * 128 +
                 ((pcol * 2) ^ ((prow & 7) << 4)))) = f2bf(pv);
      }
    }
#pragma unroll
    for (int j = 0; j < 4; ++j) {
#pragma unroll
      for (int msk = 1; msk < 16; msk <<= 1) tsum[j] += __shfl_xor(tsum[j], msk, 64);
      l_run[j] = l_run[j] * corr[j] + tsum[j];
    }
#pragma unroll
    for (int ent = 0; ent < 4; ++ent)
#pragma unroll
      for (int j = 0; j < 4; ++j) o_acc[ent][j] *= corr[j];

    // O += P V   (A = P from LDS, B = V^T from LDS)
#pragma unroll
    for (int ks = 0; ks < 2; ++ks) {
      bf16x8 pf = *(const bf16x8*)((char*)(&Plds[wid][0]) + ll * 128 +
                                   ((ks * 64 + lg * 16) ^ ((ll & 7) << 4)));
#pragma unroll
      for (int ent = 0; ent < 4; ++ent) {
        int er = ent * 16 + ll;
        bf16x8 vf = *(const bf16x8*)((char*)Vlds + er * 128 +
                                     ((ks * 64 + lg * 16) ^ ((er & 7) << 4)));
        o_acc[ent] = __builtin_amdgcn_mfma_f32_16x16x32_bf16(pf, vf, o_acc[ent], 0, 0, 0);
      }
    }
    __syncthreads();
  }

  // normalize + write [b, s, h*64+e] bf16
#pragma unroll
  for (int ent = 0; ent < 4; ++ent) {
#pragma unroll
    for (int j = 0; j < 4; ++j) {
      int qg = qbase + wid * 16 + lg * 4 + j;
      float o = o_acc[ent][j] / l_run[j];
      AO[(size_t)(b * S_ + qg) * D_ + h * E_ + ent * 16 + ll] = f2bf(o);
    }
  }
}

// ---------------- launcher ----------------

extern "C" void kernel_launch(void* const* d_in, const int* in_sizes, int n_in,
                              void* d_out, int out_size, void* d_ws, size_t ws_size,
                              hipStream_t stream) {
  const float* embedded = (const float*)d_in[0];
  const float* Wq = (const float*)d_in[1];
  const float* Wk = (const float*)d_in[2];
  const float* Wv = (const float*)d_in[3];
  const float* Wo = (const float*)d_in[4];
  const float* bo = (const float*)d_in[5];
  float* out = (float*)d_out;

  char* ws = (char*)d_ws;
  u16* X    = (u16*)(ws);                                   // 8192*1024 bf16 (16.78 MB)
  u16* Wqkv = (u16*)(ws + (16u << 20));                     // 3072*1024 (6.29 MB)
  u16* WoT  = (u16*)(ws + (16u << 20) + (6u << 20));        // 1024*1024 (2.10 MB)
  u16* QKV  = (u16*)(ws + (26u << 20));                     // 8192*3072 (50.33 MB)
  u16* AO   = (u16*)(ws + (26u << 20) + (48u << 20) + (4u << 20)); // 8192*1024
  // offsets: X@0, Wqkv@16M, WoT@22M (within 26M), QKV@26M..76.3M, AO@78M..94.8M

  // 1) embedded fp32 -> bf16  (8,388,608 elems = 2,097,152 float4)
  cvt4<<<8192, 256, 0, stream>>>(embedded, X, 2097152);
  // 2) W_qkv repack+cast (1,048,576 threads)
  cvt_wqkv<<<4096, 256, 0, stream>>>(Wq, Wk, Wv, Wqkv);
  // 3) Wo cast (already [N][K] layout for x @ Wo^T)
  cvt4<<<1024, 256, 0, stream>>>(Wo, WoT, 262144);
  // 4) QKV projection: [8192,1024] x [1024,3072]
  gemm_bt<false><<<dim3(64, 24), 256, 0, stream>>>(X, Wqkv, QKV, nullptr,
                                                   M_, NQKV_, 1024);
  // 5) causal flash attention
  attn<<<dim3(32, 64), 256, 0, stream>>>(QKV, AO);
  // 6) output projection + bias -> fp32 d_out
  gemm_bt<true><<<dim3(64, 8), 256, 0, stream>>>(AO, WoT, out, bo,
                                                 M_, 1024, 1024);
}

// Round 4
// 362.935 us; speedup vs baseline: 1.2215x; 1.2215x over previous
//
#include <hip/hip_runtime.h>
#include <hip/hip_bf16.h>

// Problem: B=4, S=2048, D=1024, H=16, E=64
#define B_ 4
#define S_ 2048
#define D_ 1024
#define H_ 16
#define E_ 64
#define M_ (B_*S_)      // 8192 rows
#define NQKV_ 3072

typedef __attribute__((ext_vector_type(8))) short bf16x8;
typedef __attribute__((ext_vector_type(4))) float f32x4;
typedef __attribute__((ext_vector_type(4))) unsigned short u16x4;
typedef unsigned short u16;

static __device__ __forceinline__ u16 f2bf(float f) {
  unsigned u = __builtin_bit_cast(unsigned, f);
  unsigned r = (u + 0x7FFFu + ((u >> 16) & 1u)) >> 16;
  return (u16)r;
}

// ---------------- conversion kernels ----------------

__global__ __launch_bounds__(256) void cvt4(const float* __restrict__ in,
                                            u16* __restrict__ out, int n4) {
  int i = blockIdx.x * 256 + threadIdx.x;
  if (i >= n4) return;
  f32x4 v = ((const f32x4*)in)[i];
  u16x4 o;
  o.x = f2bf(v.x); o.y = f2bf(v.y); o.z = f2bf(v.z); o.w = f2bf(v.w);
  ((u16x4*)out)[i] = o;
}

// Wq/Wk/Wv [H,D,E] -> Wt [3072][1024] (B^T layout: Wt[n][k] = W[k][n])
__global__ __launch_bounds__(256) void cvt_wqkv(const float* __restrict__ Wq,
                                                const float* __restrict__ Wk,
                                                const float* __restrict__ Wv,
                                                u16* __restrict__ Wt) {
  int idx = blockIdx.x * 256 + threadIdx.x;   // over [H][D][E]
  int e = idx & 63, d = (idx >> 6) & 1023, h = idx >> 16;
  int n = h * 64 + e;
  Wt[(size_t)n * 1024 + d]          = f2bf(Wq[idx]);
  Wt[(size_t)(1024 + n) * 1024 + d] = f2bf(Wk[idx]);
  Wt[(size_t)(2048 + n) * 1024 + d] = f2bf(Wv[idx]);
}

// ---------------- GEMM: C[M,N] = A[M,K] * Bt[N,K]^T ----------------
// 128x128 tile, BK=32, 4 waves (2x2 of 64x64), global_load_lds w=16.
// bf16 out: C row stride ldC. If Vt!=null, column-blocks bn>=16 (cols 2048+)
// are written TRANSPOSED into Vt[(b*1024 + (c-2048))*2048 + s] instead.

template<bool FP32OUT>
__global__ __launch_bounds__(256) void gemm_bt(const u16* __restrict__ A,
                                               const u16* __restrict__ Bt,
                                               void* __restrict__ Cv, int ldC,
                                               u16* __restrict__ Vt,
                                               const float* __restrict__ bias,
                                               int M, int N, int K) {
  __shared__ u16 As[128 * 32];
  __shared__ u16 Bs[128 * 32];
  const int tid = threadIdx.x;
  const int lane = tid & 63, wid = tid >> 6;
  const int bm = blockIdx.x, bn = blockIdx.y;
  const int wr = wid >> 1, wc = wid & 1;
  const int ll = lane & 15, lg = lane >> 4;

  f32x4 acc[4][4] = {};

  const int srow = lane >> 2;          // row within 16-row chunk
  const int scol = (lane & 3) * 8;     // element col within BK=32

  for (int k0 = 0; k0 < K; k0 += 32) {
#pragma unroll
    for (int p = 0; p < 2; ++p) {
      int row = p * 64 + wid * 16 + srow;
      const u16* ga = A + (size_t)(bm * 128 + row) * K + k0 + scol;
      __builtin_amdgcn_global_load_lds(
          (const __attribute__((address_space(1))) void*)ga,
          (__attribute__((address_space(3))) void*)(As + p * 2048 + wid * 512),
          16, 0, 0);
      const u16* gb = Bt + (size_t)(bn * 128 + row) * K + k0 + scol;
      __builtin_amdgcn_global_load_lds(
          (const __attribute__((address_space(1))) void*)gb,
          (__attribute__((address_space(3))) void*)(Bs + p * 2048 + wid * 512),
          16, 0, 0);
    }
    __syncthreads();
    bf16x8 af[4], bfr[4];
#pragma unroll
    for (int mi = 0; mi < 4; ++mi)
      af[mi] = *(const bf16x8*)&As[(wr * 64 + mi * 16 + ll) * 32 + lg * 8];
#pragma unroll
    for (int ni = 0; ni < 4; ++ni)
      bfr[ni] = *(const bf16x8*)&Bs[(wc * 64 + ni * 16 + ll) * 32 + lg * 8];
#pragma unroll
    for (int mi = 0; mi < 4; ++mi)
#pragma unroll
      for (int ni = 0; ni < 4; ++ni)
        acc[mi][ni] = __builtin_amdgcn_mfma_f32_16x16x32_bf16(af[mi], bfr[ni],
                                                              acc[mi][ni], 0, 0, 0);
    __syncthreads();
  }

  // epilogue: C/D layout col = lane&15, row = (lane>>4)*4 + reg
  const int crow0 = bm * 128 + wr * 64;
  const int ccol0 = bn * 128 + wc * 64 + ll;
  const bool vblk = (Vt != nullptr) && (bn >= 16);   // uniform per block
#pragma unroll
  for (int mi = 0; mi < 4; ++mi) {
#pragma unroll
    for (int ni = 0; ni < 4; ++ni) {
      int c = ccol0 + ni * 16;
      if (vblk) {
        int r0 = crow0 + mi * 16 + lg * 4;       // token of j=0 (mult of 4)
        int bb = r0 >> 11, s0 = r0 & 2047;
        u16x4 pk;
        pk.x = f2bf(acc[mi][ni][0]); pk.y = f2bf(acc[mi][ni][1]);
        pk.z = f2bf(acc[mi][ni][2]); pk.w = f2bf(acc[mi][ni][3]);
        *(u16x4*)&Vt[((size_t)(bb * 1024 + (c - 2048))) * 2048 + s0] = pk;
      } else {
#pragma unroll
        for (int j = 0; j < 4; ++j) {
          int r = crow0 + mi * 16 + lg * 4 + j;
          if (FP32OUT) {
            ((float*)Cv)[(size_t)r * ldC + c] = acc[mi][ni][j] + bias[c];
          } else {
            ((u16*)Cv)[(size_t)r * ldC + c] = f2bf(acc[mi][ni][j]);
          }
        }
      }
    }
  }
}

// ---------------- flash attention (causal) ----------------
// grid (16 q-tiles of 128, 64 b*h), 256 threads = 4 waves x 32 q-rows (2 groups).
// QK: [8192][2048] bf16 (Q cols 0..1023, K cols 1024..2047, per-head 64).
// Vt: [64 bh][64 e][2048 s] bf16 (V transposed).
// AO: [8192][1024] bf16.
// K/V staged via global_load_lds into linear LDS with INVERSE-swizzled global
// source; reads use byte_off ^ ((row&7)<<4)  (rule-21 both-sides pattern).

__global__ __launch_bounds__(256) void attn(const u16* __restrict__ QK,
                                            const u16* __restrict__ Vt,
                                            u16* __restrict__ AO) {
  __shared__ u16 Klds[2][4096];      // [key 0..63][e 0..63], swizzled
  __shared__ u16 Vlds[2][4096];      // V^T: [e][key], swizzled
  __shared__ u16 Plds[4][1024];      // per-wave P [16 q][64 key], swizzled

  const int qt = 15 - blockIdx.x;    // heavy blocks first
  const int bh = blockIdx.y;
  const int b = bh >> 4, h = bh & 15;
  const int tid = threadIdx.x, lane = tid & 63, wid = tid >> 6;
  const int ll = lane & 15, lg = lane >> 4;
  const int qbase = qt * 128;
  const int nkt = 2 * qt + 2;

  // Q fragments: group g rows qbase + wid*32 + g*16 + ll
  bf16x8 qf[2][2];
#pragma unroll
  for (int g = 0; g < 2; ++g)
#pragma unroll
    for (int ks = 0; ks < 2; ++ks)
      qf[g][ks] = *(const bf16x8*)(QK +
          (size_t)(b * S_ + qbase + wid * 32 + g * 16 + ll) * 2048 +
          h * E_ + ks * 32 + lg * 8);

  float m_run[2][4], l_run[2][4];
  f32x4 o_acc[2][4] = {};
#pragma unroll
  for (int g = 0; g < 2; ++g)
#pragma unroll
    for (int j = 0; j < 4; ++j) { m_run[g][j] = -INFINITY; l_run[g][j] = 0.f; }

  auto stage = [&](int buf, int kt) {
    const int kb = kt * 64;
#pragma unroll
    for (int p = 0; p < 2; ++p) {
      int d = (wid * 2 + p) * 1024 + lane * 16;    // linear LDS byte dest
      int r = d >> 7;                              // row 0..63
      int cb = (d & 127) ^ ((r & 7) << 4);         // inverse-swizzled col byte
      const char* ksrc =
          (const char*)(QK + (size_t)(b * S_ + kb + r) * 2048 + 1024 + h * E_) + cb;
      __builtin_amdgcn_global_load_lds(
          (const __attribute__((address_space(1))) void*)ksrc,
          (__attribute__((address_space(3))) void*)((char*)&Klds[buf][0] +
                                                    (wid * 2 + p) * 1024),
          16, 0, 0);
      const char* vsrc =
          (const char*)(Vt + (size_t)(bh * 64 + r) * 2048 + kb) + cb;
      __builtin_amdgcn_global_load_lds(
          (const __attribute__((address_space(1))) void*)vsrc,
          (__attribute__((address_space(3))) void*)((char*)&Vlds[buf][0] +
                                                    (wid * 2 + p) * 1024),
          16, 0, 0);
    }
  };

  stage(0, 0);
  __syncthreads();

  for (int kt = 0; kt < nkt; ++kt) {
    const int cur = kt & 1;
    if (kt + 1 < nkt) stage(cur ^ 1, kt + 1);
    const int kb = kt * 64;
    const bool need_mask = (kt >= 2 * qt);

#pragma unroll
    for (int g = 0; g < 2; ++g) {
      // S = Q K^T
      f32x4 s[4] = {};
#pragma unroll
      for (int ks = 0; ks < 2; ++ks) {
#pragma unroll
        for (int nt = 0; nt < 4; ++nt) {
          int krow = nt * 16 + ll;
          bf16x8 kf = *(const bf16x8*)((const char*)&Klds[cur][0] +
                        ((krow * 128 + ks * 64 + lg * 16) ^ ((krow & 7) << 4)));
          s[nt] = __builtin_amdgcn_mfma_f32_16x16x32_bf16(qf[g][ks], kf, s[nt],
                                                          0, 0, 0);
        }
      }
      // scale + causal mask
      const int qr0 = qbase + wid * 32 + g * 16 + lg * 4;
#pragma unroll
      for (int nt = 0; nt < 4; ++nt) {
        int keyg = kb + nt * 16 + ll;
#pragma unroll
        for (int j = 0; j < 4; ++j) {
          float sv = s[nt][j] * 0.125f;   // 1/sqrt(64)
          if (need_mask && keyg > qr0 + j) sv = -1e30f;
          s[nt][j] = sv;
        }
      }
      // online softmax (row r = lg*4+j across the 16 lanes sharing lg)
      float corr[4];
#pragma unroll
      for (int j = 0; j < 4; ++j) {
        float tm = fmaxf(fmaxf(s[0][j], s[1][j]), fmaxf(s[2][j], s[3][j]));
#pragma unroll
        for (int msk = 1; msk < 16; msk <<= 1) tm = fmaxf(tm, __shfl_xor(tm, msk, 64));
        float mn = fmaxf(m_run[g][j], tm);
        corr[j] = __expf(m_run[g][j] - mn);
        m_run[g][j] = mn;
      }
      float tsum[4] = {0.f, 0.f, 0.f, 0.f};
#pragma unroll
      for (int nt = 0; nt < 4; ++nt) {
#pragma unroll
        for (int j = 0; j < 4; ++j) {
          float pv = __expf(s[nt][j] - m_run[g][j]);
          tsum[j] += pv;
          int prow = lg * 4 + j;
          int pcol = nt * 16 + ll;
          *((u16*)((char*)&Plds[wid][0] +
                   ((prow * 128 + pcol * 2) ^ ((prow & 7) << 4)))) = f2bf(pv);
        }
      }
#pragma unroll
      for (int j = 0; j < 4; ++j) {
#pragma unroll
        for (int msk = 1; msk < 16; msk <<= 1) tsum[j] += __shfl_xor(tsum[j], msk, 64);
        l_run[g][j] = l_run[g][j] * corr[j] + tsum[j];
      }
#pragma unroll
      for (int ent = 0; ent < 4; ++ent)
#pragma unroll
        for (int j = 0; j < 4; ++j) o_acc[g][ent][j] *= corr[j];

      // O += P V   (A = P from own-wave LDS, B = V^T rows; same-wave DS ordering)
#pragma unroll
      for (int ks = 0; ks < 2; ++ks) {
        bf16x8 pf = *(const bf16x8*)((const char*)&Plds[wid][0] +
                      ((ll * 128 + ks * 64 + lg * 16) ^ ((ll & 7) << 4)));
#pragma unroll
        for (int ent = 0; ent < 4; ++ent) {
          int er = ent * 16 + ll;
          bf16x8 vf = *(const bf16x8*)((const char*)&Vlds[cur][0] +
                        ((er * 128 + ks * 64 + lg * 16) ^ ((er & 7) << 4)));
          o_acc[g][ent] = __builtin_amdgcn_mfma_f32_16x16x32_bf16(pf, vf,
                                                                 o_acc[g][ent],
                                                                 0, 0, 0);
        }
      }
    }
    __syncthreads();
  }

  // normalize + write
#pragma unroll
  for (int g = 0; g < 2; ++g)
#pragma unroll
    for (int ent = 0; ent < 4; ++ent)
#pragma unroll
      for (int j = 0; j < 4; ++j) {
        int qg = qbase + wid * 32 + g * 16 + lg * 4 + j;
        AO[(size_t)(b * S_ + qg) * D_ + h * E_ + ent * 16 + ll] =
            f2bf(o_acc[g][ent][j] / l_run[g][j]);
      }
}

// ---------------- launcher ----------------

extern "C" void kernel_launch(void* const* d_in, const int* in_sizes, int n_in,
                              void* d_out, int out_size, void* d_ws, size_t ws_size,
                              hipStream_t stream) {
  const float* embedded = (const float*)d_in[0];
  const float* Wq = (const float*)d_in[1];
  const float* Wk = (const float*)d_in[2];
  const float* Wv = (const float*)d_in[3];
  const float* Wo = (const float*)d_in[4];
  const float* bo = (const float*)d_in[5];
  float* out = (float*)d_out;

  char* ws = (char*)d_ws;
  u16* X    = (u16*)(ws);                     // [8192][1024]  16 MiB @ 0
  u16* Wqkv = (u16*)(ws + (16u << 20));       // [3072][1024]   6 MiB @ 16M
  u16* WoT  = (u16*)(ws + (22u << 20));       // [1024][1024]   2 MiB @ 22M
  u16* QK   = (u16*)(ws + (24u << 20));       // [8192][2048]  32 MiB @ 24M
  u16* Vt   = (u16*)(ws + (56u << 20));       // [64][64][2048] 16 MiB @ 56M
  u16* AO   = (u16*)(ws + (72u << 20));       // [8192][1024]  16 MiB @ 72M (ends 88M)

  // 1) embedded fp32 -> bf16
  cvt4<<<8192, 256, 0, stream>>>(embedded, X, 2097152);
  // 2) W_qkv repack+cast
  cvt_wqkv<<<4096, 256, 0, stream>>>(Wq, Wk, Wv, Wqkv);
  // 3) Wo cast
  cvt4<<<1024, 256, 0, stream>>>(Wo, WoT, 262144);
  // 4) QKV projection: QK normal (stride 2048), V transposed into Vt
  gemm_bt<false><<<dim3(64, 24), 256, 0, stream>>>(X, Wqkv, QK, 2048, Vt,
                                                   nullptr, M_, NQKV_, 1024);
  // 5) causal flash attention
  attn<<<dim3(16, 64), 256, 0, stream>>>(QK, Vt, AO);
  // 6) output projection + bias -> fp32 d_out
  gemm_bt<true><<<dim3(64, 8), 256, 0, stream>>>(AO, WoT, out, 1024, nullptr,
                                                 bo, M_, 1024, 1024);
}

// Round 5
// 227.809 us; speedup vs baseline: 1.9461x; 1.5932x over previous
//
#include <hip/hip_runtime.h>
#include <hip/hip_bf16.h>

// Problem: B=4, S=2048, D=1024, H=16, E=64
#define B_ 4
#define S_ 2048
#define D_ 1024
#define H_ 16
#define E_ 64
#define M_ (B_*S_)      // 8192 rows
#define NQKV_ 3072

typedef __attribute__((ext_vector_type(8))) short bf16x8;
typedef __attribute__((ext_vector_type(4))) float f32x4;
typedef __attribute__((ext_vector_type(4))) unsigned short u16x4;
typedef unsigned short u16;

static __device__ __forceinline__ u16 f2bf(float f) {
  unsigned u = __builtin_bit_cast(unsigned, f);
  unsigned r = (u + 0x7FFFu + ((u >> 16) & 1u)) >> 16;
  return (u16)r;
}

// packed RNE f32x2 -> bf16x2 (low = a, high = b)
static __device__ __forceinline__ unsigned pk2(float a, float b) {
  unsigned r;
  asm("v_cvt_pk_bf16_f32 %0, %1, %2" : "=v"(r) : "v"(a), "v"(b));
  return r;
}

// ---------------- conversion kernels ----------------

__global__ __launch_bounds__(256) void cvt4(const float* __restrict__ in,
                                            u16* __restrict__ out, int n4) {
  int i = blockIdx.x * 256 + threadIdx.x;
  if (i >= n4) return;
  f32x4 v = ((const f32x4*)in)[i];
  u16x4 o;
  o.x = f2bf(v.x); o.y = f2bf(v.y); o.z = f2bf(v.z); o.w = f2bf(v.w);
  ((u16x4*)out)[i] = o;
}

// Wq/Wk/Wv [H,D,E] -> Wt [3072][1024] (B^T layout: Wt[n][k] = W[k][n])
__global__ __launch_bounds__(256) void cvt_wqkv(const float* __restrict__ Wq,
                                                const float* __restrict__ Wk,
                                                const float* __restrict__ Wv,
                                                u16* __restrict__ Wt) {
  int idx = blockIdx.x * 256 + threadIdx.x;   // over [H][D][E]
  int e = idx & 63, d = (idx >> 6) & 1023, h = idx >> 16;
  int n = h * 64 + e;
  Wt[(size_t)n * 1024 + d]          = f2bf(Wq[idx]);
  Wt[(size_t)(1024 + n) * 1024 + d] = f2bf(Wk[idx]);
  Wt[(size_t)(2048 + n) * 1024 + d] = f2bf(Wv[idx]);
}

// ---------------- GEMM: C[M,N] = A[M,K] * Bt[N,K]^T ----------------
// 128x128 tile, BK=32, 4 waves (2x2 of 64x64), global_load_lds w=16.
// If Vt!=null, column-blocks bn>=16 (cols 2048+) are written TRANSPOSED
// into Vt[(b*1024 + (c-2048))*2048 + s].

template<bool FP32OUT>
__global__ __launch_bounds__(256) void gemm_bt(const u16* __restrict__ A,
                                               const u16* __restrict__ Bt,
                                               void* __restrict__ Cv, int ldC,
                                               u16* __restrict__ Vt,
                                               const float* __restrict__ bias,
                                               int M, int N, int K) {
  __shared__ u16 As[128 * 32];
  __shared__ u16 Bs[128 * 32];
  const int tid = threadIdx.x;
  const int lane = tid & 63, wid = tid >> 6;
  const int bm = blockIdx.x, bn = blockIdx.y;
  const int wr = wid >> 1, wc = wid & 1;
  const int ll = lane & 15, lg = lane >> 4;

  f32x4 acc[4][4] = {};

  const int srow = lane >> 2;          // row within 16-row chunk
  const int scol = (lane & 3) * 8;     // element col within BK=32

  for (int k0 = 0; k0 < K; k0 += 32) {
#pragma unroll
    for (int p = 0; p < 2; ++p) {
      int row = p * 64 + wid * 16 + srow;
      const u16* ga = A + (size_t)(bm * 128 + row) * K + k0 + scol;
      __builtin_amdgcn_global_load_lds(
          (const __attribute__((address_space(1))) void*)ga,
          (__attribute__((address_space(3))) void*)(As + p * 2048 + wid * 512),
          16, 0, 0);
      const u16* gb = Bt + (size_t)(bn * 128 + row) * K + k0 + scol;
      __builtin_amdgcn_global_load_lds(
          (const __attribute__((address_space(1))) void*)gb,
          (__attribute__((address_space(3))) void*)(Bs + p * 2048 + wid * 512),
          16, 0, 0);
    }
    __syncthreads();
    bf16x8 af[4], bfr[4];
#pragma unroll
    for (int mi = 0; mi < 4; ++mi)
      af[mi] = *(const bf16x8*)&As[(wr * 64 + mi * 16 + ll) * 32 + lg * 8];
#pragma unroll
    for (int ni = 0; ni < 4; ++ni)
      bfr[ni] = *(const bf16x8*)&Bs[(wc * 64 + ni * 16 + ll) * 32 + lg * 8];
#pragma unroll
    for (int mi = 0; mi < 4; ++mi)
#pragma unroll
      for (int ni = 0; ni < 4; ++ni)
        acc[mi][ni] = __builtin_amdgcn_mfma_f32_16x16x32_bf16(af[mi], bfr[ni],
                                                              acc[mi][ni], 0, 0, 0);
    __syncthreads();
  }

  // epilogue: C/D layout col = lane&15, row = (lane>>4)*4 + reg
  const int crow0 = bm * 128 + wr * 64;
  const int ccol0 = bn * 128 + wc * 64 + ll;
  const bool vblk = (Vt != nullptr) && (bn >= 16);   // uniform per block
#pragma unroll
  for (int mi = 0; mi < 4; ++mi) {
#pragma unroll
    for (int ni = 0; ni < 4; ++ni) {
      int c = ccol0 + ni * 16;
      if (vblk) {
        int r0 = crow0 + mi * 16 + lg * 4;       // token of j=0 (mult of 4)
        int bb = r0 >> 11, s0 = r0 & 2047;
        u16x4 pkv;
        pkv.x = f2bf(acc[mi][ni][0]); pkv.y = f2bf(acc[mi][ni][1]);
        pkv.z = f2bf(acc[mi][ni][2]); pkv.w = f2bf(acc[mi][ni][3]);
        *(u16x4*)&Vt[((size_t)(bb * 1024 + (c - 2048))) * 2048 + s0] = pkv;
      } else {
#pragma unroll
        for (int j = 0; j < 4; ++j) {
          int r = crow0 + mi * 16 + lg * 4 + j;
          if (FP32OUT) {
            ((float*)Cv)[(size_t)r * ldC + c] = acc[mi][ni][j] + bias[c];
          } else {
            ((u16*)Cv)[(size_t)r * ldC + c] = f2bf(acc[mi][ni][j]);
          }
        }
      }
    }
  }
}

// ---------------- flash attention (causal), swapped-QK^T form ----------------
// Grid: 1024 flat blocks, 256 thr = 4 waves x 16 q-rows, QBLK=64, KVBLK=64.
// Block pr handles q-tiles {pr, 31-pr}: 33 k-tiles each -> perfect balance.
// Swapped mfma(K,Q): lane owns q-row = ll; permuted K-row map kappa makes
// post-exp P values exactly the PV B-fragment (zero cross-lane, no P-LDS).
// kappa(nt, r) = 32*(nt>>1) + 8*(r>>2) + 4*(nt&1) + (r&3)
// key of s[nt][j] (at lane lg) = kb + 32*(nt>>1) + lg*8 + 4*(nt&1) + j
// Swizzle: col16B-slot ^= (row&7) ^ (((row>>3)&3)<<1)  (even bank spread for
// both kappa-permuted K reads and e-major V reads).

#define SWZ(r) (((((r) & 7) ^ ((((r) >> 3) & 3) << 1))) << 4)

__global__ __launch_bounds__(256) void attn(const u16* __restrict__ QK,
                                            const u16* __restrict__ Vt,
                                            u16* __restrict__ AO) {
  __shared__ u16 Klds[2][4096];      // [key][e] swizzled, 8KB each buf
  __shared__ u16 Vlds[2][4096];      // V^T [e][key] swizzled

  // XCD-chunked remap: XCD x hosts bh in [x*8, x*8+8) -> K/V fits 4MB L2
  const int wg = blockIdx.x;                 // 0..1023
  const int lin = (wg & 7) * 128 + (wg >> 3);
  const int bh = lin >> 4, pr = lin & 15;
  const int b = bh >> 4, h = bh & 15;
  const int tid = threadIdx.x, lane = tid & 63, wid = tid >> 6;
  const int ll = lane & 15, lg = lane >> 4;

  auto stage = [&](int buf, int kb) {
#pragma unroll
    for (int p = 0; p < 2; ++p) {
      int chunk = wid * 2 + p;                 // 0..7 (1KB each)
      int r = chunk * 8 + (lane >> 3);         // tile row 0..63
      int cl = ((lane & 7) * 16) ^ SWZ(r);     // logical col byte (inv-swz src)
      const char* ksrc = (const char*)(QK +
          (size_t)(b * S_ + kb + r) * 2048 + 1024 + h * E_) + cl;
      __builtin_amdgcn_global_load_lds(
          (const __attribute__((address_space(1))) void*)ksrc,
          (__attribute__((address_space(3))) void*)((char*)&Klds[buf][0] + chunk * 1024),
          16, 0, 0);
      const char* vsrc = (const char*)(Vt + (size_t)(bh * 64 + r) * 2048 + kb) + cl;
      __builtin_amdgcn_global_load_lds(
          (const __attribute__((address_space(1))) void*)vsrc,
          (__attribute__((address_space(3))) void*)((char*)&Vlds[buf][0] + chunk * 1024),
          16, 0, 0);
    }
  };

  const float SC = 0.18033688011f;   // log2(e)/8  (exp2-domain softmax)

  int cur = 0;
  stage(0, 0);                       // phase 0, kt 0

  for (int ph = 0; ph < 2; ++ph) {
    const int qt = ph ? 31 - pr : pr;
    const int nkt = qt + 1;
    const int qbase = qt * 64;
    const int q = qbase + wid * 16 + ll;

    // Q fragments (B-operand): col = ll -> q-row, k = e chunk lg*8
    const u16* qp = QK + (size_t)(b * S_ + q) * 2048 + h * E_;
    bf16x8 qf0 = *(const bf16x8*)(qp + lg * 8);
    bf16x8 qf1 = *(const bf16x8*)(qp + 32 + lg * 8);

    float m_run = -INFINITY, l_run = 0.f;
    f32x4 o_acc[4] = {};

    for (int kt = 0; kt < nkt; ++kt) {
      __syncthreads();               // staged buffer `cur` ready
      const bool havenext = (kt + 1 < nkt) || (ph == 0);
      if (havenext) stage(cur ^ 1, (kt + 1 < nkt) ? (kt + 1) * 64 : 0);

      const int kb = kt * 64;
      const bool need_mask = (kt == qt);

      // S^T = mfma(K, Q): lane -> q-row ll, 16 keys across (nt, j)
      f32x4 s[4] = {};
      __builtin_amdgcn_s_setprio(1);
#pragma unroll
      for (int ks = 0; ks < 2; ++ks) {
#pragma unroll
        for (int nt = 0; nt < 4; ++nt) {
          int krow = 32 * (nt >> 1) + ((ll >> 2) << 3) + ((nt & 1) << 2) + (ll & 3);
          bf16x8 kf = *(const bf16x8*)((const char*)&Klds[cur][0] +
                        krow * 128 + ((ks * 64 + lg * 16) ^ SWZ(krow)));
          s[nt] = __builtin_amdgcn_mfma_f32_16x16x32_bf16(
              kf, ks ? qf1 : qf0, s[nt], 0, 0, 0);
        }
      }
      __builtin_amdgcn_s_setprio(0);

      // scale (log2 domain) + causal mask
#pragma unroll
      for (int nt = 0; nt < 4; ++nt) {
        int keyb = kb + 32 * (nt >> 1) + 4 * (nt & 1) + lg * 8;
#pragma unroll
        for (int j = 0; j < 4; ++j) {
          float sv = s[nt][j] * SC;
          if (need_mask && (keyb + j > q)) sv = -1e30f;
          s[nt][j] = sv;
        }
      }

      // row softmax: in-lane tree + 2 shuffles (lanes sharing ll)
      float pm = -3.0e38f;
#pragma unroll
      for (int nt = 0; nt < 4; ++nt)
#pragma unroll
        for (int j = 0; j < 4; ++j) pm = fmaxf(pm, s[nt][j]);
      pm = fmaxf(pm, __shfl_xor(pm, 16, 64));
      pm = fmaxf(pm, __shfl_xor(pm, 32, 64));
      float mn = fmaxf(m_run, pm);
      float corr = exp2f(m_run - mn);
      m_run = mn;

      float p4[4][4];
      float ts = 0.f;
#pragma unroll
      for (int nt = 0; nt < 4; ++nt)
#pragma unroll
        for (int j = 0; j < 4; ++j) {
          float pv = exp2f(s[nt][j] - mn);
          p4[nt][j] = pv;
          ts += pv;
        }
      ts += __shfl_xor(ts, 16, 64);
      ts += __shfl_xor(ts, 32, 64);
      l_run = l_run * corr + ts;
#pragma unroll
      for (int ent = 0; ent < 4; ++ent)
#pragma unroll
        for (int j = 0; j < 4; ++j) o_acc[ent][j] *= corr;

      // O^T += V^T P : A = V^T (rows e), B = P (in-register, col = q-row ll)
      __builtin_amdgcn_s_setprio(1);
#pragma unroll
      for (int ks = 0; ks < 2; ++ks) {
        union { unsigned w[4]; bf16x8 v; } pf;
        pf.w[0] = pk2(p4[2 * ks][0], p4[2 * ks][1]);
        pf.w[1] = pk2(p4[2 * ks][2], p4[2 * ks][3]);
        pf.w[2] = pk2(p4[2 * ks + 1][0], p4[2 * ks + 1][1]);
        pf.w[3] = pk2(p4[2 * ks + 1][2], p4[2 * ks + 1][3]);
#pragma unroll
        for (int ent = 0; ent < 4; ++ent) {
          int vrow = ent * 16 + ll;
          bf16x8 vf = *(const bf16x8*)((const char*)&Vlds[cur][0] +
                        vrow * 128 + ((ks * 64 + lg * 16) ^ SWZ(vrow)));
          o_acc[ent] = __builtin_amdgcn_mfma_f32_16x16x32_bf16(
              vf, pf.v, o_acc[ent], 0, 0, 0);
        }
      }
      __builtin_amdgcn_s_setprio(0);

      cur ^= 1;
    }

    // epilogue: O[e = ent*16+lg*4+j][q = ll]; AO write u16x4 along j
    float rl = 1.0f / l_run;
#pragma unroll
    for (int ent = 0; ent < 4; ++ent) {
      u16x4 o;
#pragma unroll
      for (int j = 0; j < 4; ++j) o[j] = f2bf(o_acc[ent][j] * rl);
      *(u16x4*)&AO[(size_t)(b * S_ + q) * D_ + h * E_ + ent * 16 + lg * 4] = o;
    }
  }
}

// ---------------- launcher ----------------

extern "C" void kernel_launch(void* const* d_in, const int* in_sizes, int n_in,
                              void* d_out, int out_size, void* d_ws, size_t ws_size,
                              hipStream_t stream) {
  const float* embedded = (const float*)d_in[0];
  const float* Wq = (const float*)d_in[1];
  const float* Wk = (const float*)d_in[2];
  const float* Wv = (const float*)d_in[3];
  const float* Wo = (const float*)d_in[4];
  const float* bo = (const float*)d_in[5];
  float* out = (float*)d_out;

  char* ws = (char*)d_ws;
  u16* X    = (u16*)(ws);                     // [8192][1024]  16 MiB @ 0
  u16* Wqkv = (u16*)(ws + (16u << 20));       // [3072][1024]   6 MiB @ 16M
  u16* WoT  = (u16*)(ws + (22u << 20));       // [1024][1024]   2 MiB @ 22M
  u16* QK   = (u16*)(ws + (24u << 20));       // [8192][2048]  32 MiB @ 24M
  u16* Vt   = (u16*)(ws + (56u << 20));       // [64][64][2048] 16 MiB @ 56M
  u16* AO   = (u16*)(ws + (72u << 20));       // [8192][1024]  16 MiB @ 72M

  // 1) embedded fp32 -> bf16
  cvt4<<<8192, 256, 0, stream>>>(embedded, X, 2097152);
  // 2) W_qkv repack+cast
  cvt_wqkv<<<4096, 256, 0, stream>>>(Wq, Wk, Wv, Wqkv);
  // 3) Wo cast
  cvt4<<<1024, 256, 0, stream>>>(Wo, WoT, 262144);
  // 4) QKV projection: QK normal (stride 2048), V transposed into Vt
  gemm_bt<false><<<dim3(64, 24), 256, 0, stream>>>(X, Wqkv, QK, 2048, Vt,
                                                   nullptr, M_, NQKV_, 1024);
  // 5) causal flash attention (folded-pair balanced grid)
  attn<<<1024, 256, 0, stream>>>(QK, Vt, AO);
  // 6) output projection + bias -> fp32 d_out
  gemm_bt<true><<<dim3(64, 8), 256, 0, stream>>>(AO, WoT, out, 1024, nullptr,
                                                 bo, M_, 1024, 1024);
}